// Round 11
// baseline (324.840 us; speedup 1.0000x reference)
//
#include <hip/hip_runtime.h>
#include <hip/hip_bf16.h>

#define BSZ 8
#define CDIM 512
#define KDIM 512
#define HWSZ 16384   // 128*128
#define NPIX (BSZ*HWSZ)  // 131072

using bf16x8 = __attribute__((ext_vector_type(8))) short;
using f32x4  = __attribute__((ext_vector_type(4))) float;
typedef unsigned long long u64;

__device__ __forceinline__ unsigned pack2bf16(float lo, float hi) {
  // truncating f32->bf16 pair pack: lo -> bits[15:0], hi -> bits[31:16]
  return (__builtin_bit_cast(unsigned, lo) >> 16) |
         (__builtin_bit_cast(unsigned, hi) & 0xFFFF0000u);
}

// async global->LDS, 16B per lane; LDS dest = wave-uniform base + lane*16 (m104)
__device__ __forceinline__ void gload_lds16(const unsigned short* g, unsigned short* l) {
  __builtin_amdgcn_global_load_lds(
      (const __attribute__((address_space(1))) unsigned int*)g,
      (__attribute__((address_space(3))) unsigned int*)l, 16, 0, 0);
}

// ---------------- prep: normalize embeddings (plain + [ks][cls][32c] tiled) + zero counters ----------------
__global__ __launch_bounds__(64) void prep_emb_kernel(const float* __restrict__ E,
                                                      unsigned short* __restrict__ Eb,
                                                      unsigned short* __restrict__ EbT,
                                                      float* __restrict__ counters) {
  int k = blockIdx.x;
  int lane = threadIdx.x;
  if (k == 0) {   // zero gt_count/pred_count/inter (6 KB); rocclr fill path is pathological
    uint4 z = {0u, 0u, 0u, 0u};
    #pragma unroll
    for (int j = 0; j < 6; ++j) ((uint4*)counters)[lane + 64 * j] = z;
  }
  const float4* row = (const float4*)(E + (size_t)k * CDIM);
  float4 v0 = row[lane * 2], v1 = row[lane * 2 + 1];
  float ss = v0.x*v0.x + v0.y*v0.y + v0.z*v0.z + v0.w*v0.w
           + v1.x*v1.x + v1.y*v1.y + v1.z*v1.z + v1.w*v1.w;
  #pragma unroll
  for (int d = 1; d < 64; d <<= 1) ss += __shfl_xor(ss, d, 64);
  float rinv = rsqrtf(fmaxf(ss, 1e-24f));
  float f[8] = {v0.x, v0.y, v0.z, v0.w, v1.x, v1.y, v1.z, v1.w};
  unsigned o[8];
  #pragma unroll
  for (int e = 0; e < 8; ++e) {
    float x = f[e] * rinv;
    unsigned u = __builtin_bit_cast(unsigned, x);
    o[e] = (u + 0x7FFFu + ((u >> 16) & 1u)) >> 16;   // RNE f32->bf16
  }
  uint4 pack;
  pack.x = o[0] | (o[1] << 16);
  pack.y = o[2] | (o[3] << 16);
  pack.z = o[4] | (o[5] << 16);
  pack.w = o[6] | (o[7] << 16);
  ((uint4*)(Eb + (size_t)k * CDIM))[lane] = pack;
  // tiled: EbT[ks][cls][32c]; lane covers c = lane*8..+7 -> ks = lane>>2, q4 = lane&3
  int ks = lane >> 2, q4 = lane & 3;
  *(uint4*)(EbT + ((size_t)ks * 512 + k) * 32 + q4 * 8) = pack;
}

// ---------------- gt_count[k] (fallback path only) ----------------
__global__ __launch_bounds__(256) void gt_count_kernel(const float* __restrict__ ANN,
                                                       float* __restrict__ gt_count) {
  int slice = blockIdx.x;
  int k = slice & (KDIM - 1);
  const float4* p = (const float4*)(ANN + (size_t)slice * HWSZ);
  float s = 0.f;
  #pragma unroll
  for (int i = 0; i < 16; ++i) {
    float4 v = p[threadIdx.x + i * 256];
    s += v.x + v.y + v.z + v.w;
  }
  #pragma unroll
  for (int d = 1; d < 64; d <<= 1) s += __shfl_xor(s, d, 64);
  __shared__ float sw[4];
  if ((threadIdx.x & 63) == 0) sw[threadIdx.x >> 6] = s;
  __syncthreads();
  if (threadIdx.x == 0) atomicAdd(&gt_count[k], sw[0] + sw[1] + sw[2] + sw[3]);
}

// ---------------- pass 1: X -> XtT (tiled bf16), DRAM-row-friendly ----------------
// tile = 1024 px x 32 c (one k-step). X reads: 32 rows x 4KB contiguous per block.
// Stores: 1KB runs in tiled XtT[pxb64][ks][64px][32c] layout (gemm staging order).
__global__ __launch_bounds__(256) void transpose_v3_kernel(
    const float* __restrict__ X, unsigned short* __restrict__ XtT) {
  __shared__ unsigned int lds[16 * 1024];    // 16 c-pairs x 1024 px
  int t = threadIdx.x, w = t >> 6, l = t & 63;
  int bid = blockIdx.x;                      // 2048 = 128 px-tiles x 16 ks
  int pt = bid >> 4, ks = bid & 15;          // consecutive blocks share the px-window
  int px0 = pt << 10;
  int b = px0 >> 14, hw = px0 & (HWSZ - 1);
  const float* xb = X + ((size_t)b * CDIM + ks * 32 + 8 * w) * HWSZ + hw + 4 * l;

  // 32 independent 4KB-run loads per wave (8 rows x 4 segments)
  float4 xv[8][4];
  #pragma unroll
  for (int r = 0; r < 8; ++r)
    #pragma unroll
    for (int s = 0; s < 4; ++s)
      xv[r][s] = *(const float4*)(xb + (size_t)r * HWSZ + s * 256);

  // pack c-pairs -> swizzled LDS (row = c-pair, col = px)
  #pragma unroll
  for (int rp = 0; rp < 4; ++rp) {
    int cp = 4 * w + rp;
    int swz = (cp & 7) << 2;
    #pragma unroll
    for (int s = 0; s < 4; ++s) {
      unsigned pk[4];
      #pragma unroll
      for (int j = 0; j < 4; ++j)
        pk[j] = pack2bf16(((const float*)&xv[2 * rp][s])[j],
                          ((const float*)&xv[2 * rp + 1][s])[j]);
      *(uint4*)&lds[cp * 1024 + ((s * 256 + 4 * l) ^ swz)] = *(const uint4*)pk;
    }
  }
  __syncthreads();

  // transpose-read (4x b32, 2-way banks) and store 1KB runs in tiled layout
  #pragma unroll
  for (int rr = 0; rr < 16; ++rr) {
    int ch = rr * 256 + t;
    int q4 = ch & 3, pxl = ch >> 2;
    unsigned o[4];
    #pragma unroll
    for (int j = 0; j < 4; ++j) {
      int cp = 4 * q4 + j;
      o[j] = lds[cp * 1024 + (pxl ^ ((cp & 7) << 2))];
    }
    int pxg = px0 + pxl;
    *(uint4*)(XtT + ((size_t)(pxg >> 6) * 16 + ks) * 2048 + (size_t)(pxg & 63) * 32 + q4 * 8)
        = *(const uint4*)o;
  }
}

// ---------------- pass 2 mega: even blocks = GEMM(64px x 512cls) + argmax + counts;
//                  odd blocks = ANN gt-count stream (block-level overlap, no coupling) ----------------
__global__ __launch_bounds__(512, 4) void mega_kernel(
    const unsigned short* __restrict__ XtT, const unsigned short* __restrict__ EbT,
    const float* __restrict__ ANN, float* __restrict__ gt_count,
    int* __restrict__ pred_count, int* __restrict__ inter) {
  __shared__ unsigned short As[2][64 * 32];      // 8 KB
  __shared__ unsigned short Bs[2][512 * 32];     // 64 KB
  __shared__ float s_v[8][64];
  __shared__ int   s_k[8][64];
  __shared__ float sgt[8];
  int t = threadIdx.x;
  int bid = blockIdx.x;

  if (bid & 1) {
    // ---- gt-count block: 2 exact (b,k) ANN slices, high-MLP stream ----
    int g = bid >> 1;
    int which = t >> 8, tt = t & 255, w = t >> 6, lane = t & 63;
    const float* Ap = ANN + (size_t)(2 * g + which) * HWSZ + tt * 4;
    float s = 0.f;
    #pragma unroll
    for (int i = 0; i < 16; ++i) {
      float4 v = *(const float4*)(Ap + (size_t)i * 1024);
      s += (v.x + v.y) + (v.z + v.w);
    }
    #pragma unroll
    for (int d = 1; d < 64; d <<= 1) s += __shfl_xor(s, d, 64);
    if (lane == 0) sgt[w] = s;
    __syncthreads();
    // exact integer partials -> order-independent float atomics
    if (t == 0)   atomicAdd(&gt_count[(2 * g)     & (KDIM - 1)], sgt[0] + sgt[1] + sgt[2] + sgt[3]);
    if (t == 256) atomicAdd(&gt_count[(2 * g + 1) & (KDIM - 1)], sgt[4] + sgt[5] + sgt[6] + sgt[7]);
    return;
  }

  // ---- gemm block: 64 px x 512 cls; 8 waves, wave = 64px x 64cls, acc[4][4] ----
  int pxblk = bid >> 1;
  int px0 = pxblk * 64;
  int b = px0 >> 14, hw = px0 & (HWSZ - 1);
  int lane = t & 63, wv = t >> 6;
  int p15 = lane & 15, q = lane >> 4;

  const unsigned short* Abase = XtT + (size_t)pxblk * 32768;   // 16 slabs x 2048 ushort
  // B slab i: EbT + i*16384 (512cls x 32c)
  #define STAGE(buf, i)                                                               \
    {                                                                                 \
      _Pragma("unroll")                                                               \
      for (int j = 0; j < 4; ++j)                                                     \
        gload_lds16(EbT + (size_t)(i) * 16384 + ((size_t)t + 512 * j) * 8,            \
                    &Bs[buf][(t & ~63) * 8 + j * 4096]);                              \
      if (t < 256)                                                                    \
        gload_lds16(Abase + (size_t)(i) * 2048 + (size_t)t * 8,                       \
                    &As[buf][(t & ~63) * 8]);                                         \
    }

  f32x4 acc[4][4];
  #pragma unroll
  for (int m = 0; m < 4; ++m)
    #pragma unroll
    for (int n = 0; n < 4; ++n)
      acc[m][n] = (f32x4){0.f, 0.f, 0.f, 0.f};

  STAGE(0, 0);
  for (int i = 0; i < 16; ++i) {
    int cur = i & 1;
    if (i < 15) STAGE(cur ^ 1, i + 1);
    __syncthreads();                          // drains gload_lds: buf[cur] ready
    bf16x8 a[4], bfr[4];
    #pragma unroll
    for (int m = 0; m < 4; ++m)
      a[m] = *(bf16x8*)&As[cur][(m * 16 + p15) * 32 + q * 8];
    #pragma unroll
    for (int n = 0; n < 4; ++n)
      bfr[n] = *(bf16x8*)&Bs[cur][(wv * 64 + n * 16 + p15) * 32 + q * 8];
    #pragma unroll
    for (int n = 0; n < 4; ++n)
      #pragma unroll
      for (int m = 0; m < 4; ++m)
        acc[m][n] = __builtin_amdgcn_mfma_f32_16x16x32_bf16(a[m], bfr[n], acc[m][n], 0, 0, 0);
    __syncthreads();                          // reads done before next stage overwrites
  }
  #undef STAGE

  // per-wave argmax over its 64 cls; D layout: col(cls)=lane&15, row(px)=q*4+reg
  #pragma unroll
  for (int m = 0; m < 4; ++m) {
    #pragma unroll
    for (int r = 0; r < 4; ++r) {
      float best = acc[m][0][r];
      int bn = 0;
      #pragma unroll
      for (int n = 1; n < 4; ++n) {
        float v = acc[m][n][r];
        if (v > best) { best = v; bn = n; }
      }
      int bk = wv * 64 + bn * 16 + p15;
      #pragma unroll
      for (int d = 1; d < 16; d <<= 1) {      // butterfly over 16 cls-col lanes
        float ov = __shfl_xor(best, d, 64);
        int   ok = __shfl_xor(bk, d, 64);
        if (ov > best || (ov == best && ok < bk)) { best = ov; bk = ok; }
      }
      if (p15 == 0) {
        int p = m * 16 + q * 4 + r;           // pixel within block
        s_v[wv][p] = best;
        s_k[wv][p] = bk;
      }
    }
  }
  __syncthreads();
  if (t < 64) {
    int p = t;
    float best = s_v[0][p]; int bk = s_k[0][p];
    #pragma unroll
    for (int w = 1; w < 8; ++w) {             // waves cover ascending cls ranges
      float v = s_v[w][p]; int kk = s_k[w][p];
      if (v > best || (v == best && kk < bk)) { best = v; bk = kk; }
    }
    atomicAdd(&pred_count[bk], 1);
    float g2 = ANN[((size_t)b * KDIM + bk) * HWSZ + hw + p];  // one-hot gather
    if (g2 > 0.5f) atomicAdd(&inter[bk], 1);
  }
}

// ---------------- final dice reduction ----------------
__global__ __launch_bounds__(512) void final_kernel(
    const int* __restrict__ pred_count, const int* __restrict__ inter,
    const float* __restrict__ gt_count, float* __restrict__ out) {
  int k = threadIdx.x;
  float G = gt_count[k];
  float P = (float)pred_count[k];
  float I = (float)inter[k];
  float card  = P + G;
  float score = (2.f * I + 1e-4f) / fmaxf(card + 1e-4f, 1e-7f);
  float v = (G > 0.f) ? (1.f - score) : 0.f;
  #pragma unroll
  for (int d = 1; d < 64; d <<= 1) v += __shfl_xor(v, d, 64);
  __shared__ float sw[8];
  if ((k & 63) == 0) sw[k >> 6] = v;
  __syncthreads();
  if (k == 0) {
    float s = 0.f;
    #pragma unroll
    for (int i = 0; i < 8; ++i) s += sw[i];
    out[0] = s / (float)KDIM;
  }
}

// ---------------- fallback (only if ws too small): R1 one-pass ----------------
__global__ __launch_bounds__(256, 1) void gemm_fb(
    const float* __restrict__ X, const float* __restrict__ ANN,
    const unsigned short* __restrict__ Eb,
    int* __restrict__ pred_count, int* __restrict__ inter) {
  int tid = threadIdx.x;
  int wv = tid >> 6;
  int lane = tid & 63;
  int p15 = lane & 15, q = lane >> 4;
  int pix0 = blockIdx.x * 64;
  int b = pix0 >> 14;
  int hw = pix0 & (HWSZ - 1);
  const float*          Xb = X  + (size_t)b * CDIM * HWSZ + hw + p15;
  const unsigned short* Ew = Eb + (size_t)(wv * 128) * CDIM;
  f32x4 acc[4][8];
  #pragma unroll
  for (int m = 0; m < 4; ++m)
    #pragma unroll
    for (int n = 0; n < 8; ++n)
      acc[m][n] = (f32x4){0.f, 0.f, 0.f, 0.f};
  for (int cs = 0; cs < 16; ++cs) {
    int c0 = cs * 32 + q * 8;
    bf16x8 a[4];
    #pragma unroll
    for (int m = 0; m < 4; ++m)
      #pragma unroll
      for (int e = 0; e < 8; ++e) {
        float x = Xb[(size_t)(c0 + e) * HWSZ + m * 16];
        a[m][e] = (short)(__builtin_bit_cast(unsigned, x) >> 16);
      }
    bf16x8 bfrag[8];
    #pragma unroll
    for (int n = 0; n < 8; ++n)
      bfrag[n] = *(const bf16x8*)(Ew + (size_t)(n * 16 + p15) * CDIM + cs * 32 + q * 8);
    #pragma unroll
    for (int n = 0; n < 8; ++n)
      #pragma unroll
      for (int m = 0; m < 4; ++m)
        acc[m][n] = __builtin_amdgcn_mfma_f32_16x16x32_bf16(a[m], bfrag[n], acc[m][n], 0, 0, 0);
  }
  __shared__ float s_v[4][64];
  __shared__ int   s_k[4][64];
  #pragma unroll
  for (int m = 0; m < 4; ++m)
    #pragma unroll
    for (int r = 0; r < 4; ++r) {
      float best = acc[m][0][r];
      int bn = 0;
      #pragma unroll
      for (int n = 1; n < 8; ++n) {
        float v = acc[m][n][r];
        if (v > best) { best = v; bn = n; }
      }
      int bk = wv * 128 + bn * 16 + p15;
      #pragma unroll
      for (int d = 1; d < 16; d <<= 1) {
        float ov = __shfl_xor(best, d, 64);
        int   ok = __shfl_xor(bk, d, 64);
        if (ov > best || (ov == best && ok < bk)) { best = ov; bk = ok; }
      }
      if (p15 == 0) {
        int p = m * 16 + q * 4 + r;
        s_v[wv][p] = best;
        s_k[wv][p] = bk;
      }
    }
  __syncthreads();
  if (tid < 64) {
    int p = tid;
    float best = s_v[0][p]; int bk = s_k[0][p];
    #pragma unroll
    for (int w = 1; w < 4; ++w) {
      float v = s_v[w][p]; int kk = s_k[w][p];
      if (v > best || (v == best && kk < bk)) { best = v; bk = kk; }
    }
    atomicAdd(&pred_count[bk], 1);
    float g = ANN[((size_t)b * KDIM + bk) * HWSZ + hw + p];
    if (g > 0.5f) atomicAdd(&inter[bk], 1);
  }
}

extern "C" void kernel_launch(void* const* d_in, const int* in_sizes, int n_in,
                              void* d_out, int out_size, void* d_ws, size_t ws_size,
                              hipStream_t stream) {
  const float* X   = (const float*)d_in[0];   // [8,512,128,128] fp32
  const float* ANN = (const float*)d_in[1];   // [8,512,128,128] fp32 one-hot
  const float* E   = (const float*)d_in[2];   // [512,512] fp32

  char* base = (char*)d_ws;
  unsigned short* Eb  = (unsigned short*)base;                 // 512 KiB @0 (fallback)
  unsigned short* EbT = (unsigned short*)(base + 524288);      // 512 KiB @512K ([ks][cls][32c])
  float* gt_count     = (float*)(base + 1048576);              // 2 KiB
  int*   pred_count   = (int*)  (base + 1048576 + 2048);
  int*   inter        = (int*)  (base + 1048576 + 4096);
  unsigned short* XtT = (unsigned short*)(base + 4194304);     // 128 MiB tiled bf16

  size_t need = 4194304 + (size_t)NPIX * CDIM * 2;
  int big = (ws_size >= need) ? 1 : 0;

  prep_emb_kernel<<<KDIM, 64, 0, stream>>>(E, Eb, EbT, gt_count);
  if (big) {
    transpose_v3_kernel<<<2048, 256, 0, stream>>>(X, XtT);
    // even blocks: 2048 gemm tiles (64px x 512cls); odd blocks: 2048 gt-count streams
    mega_kernel<<<4096, 512, 0, stream>>>(XtT, EbT, ANN, gt_count, pred_count, inter);
  } else {
    gt_count_kernel<<<BSZ * KDIM, 256, 0, stream>>>(ANN, gt_count);
    gemm_fb<<<NPIX / 64, 256, 0, stream>>>(X, ANN, Eb, pred_count, inter);
  }
  final_kernel<<<1, 512, 0, stream>>>(pred_count, inter, gt_count, (float*)d_out);
}

// Round 12
// 313.393 us; speedup vs baseline: 1.0365x; 1.0365x over previous
//
#include <hip/hip_runtime.h>
#include <hip/hip_bf16.h>

#define BSZ 8
#define CDIM 512
#define KDIM 512
#define HWSZ 16384   // 128*128
#define NPIX (BSZ*HWSZ)  // 131072

#define ROWU 20      // LDS row stride in u32 (80 B): 16B-aligned, 2-way (free) r/w

using bf16x8 = __attribute__((ext_vector_type(8))) short;
using f32x4  = __attribute__((ext_vector_type(4))) float;

__device__ __forceinline__ unsigned pack2bf16(float lo, float hi) {
  // truncating f32->bf16 pair pack: lo -> bits[15:0], hi -> bits[31:16]
  return (__builtin_bit_cast(unsigned, lo) >> 16) |
         (__builtin_bit_cast(unsigned, hi) & 0xFFFF0000u);
}

// ---------------- prep: Eb[k][c] = bf16( E[k][c] / ||E[k]|| ) + zero counters ----------------
__global__ __launch_bounds__(64) void prep_emb_kernel(const float* __restrict__ E,
                                                      unsigned short* __restrict__ Eb,
                                                      float* __restrict__ counters) {
  int k = blockIdx.x;
  int lane = threadIdx.x;
  if (k == 0) {   // zero gt_count/pred_count/inter (6 KB); rocclr fill path is pathological
    uint4 z = {0u, 0u, 0u, 0u};
    #pragma unroll
    for (int j = 0; j < 6; ++j) ((uint4*)counters)[lane + 64 * j] = z;
  }
  const float4* row = (const float4*)(E + (size_t)k * CDIM);
  float4 v0 = row[lane * 2], v1 = row[lane * 2 + 1];
  float ss = v0.x*v0.x + v0.y*v0.y + v0.z*v0.z + v0.w*v0.w
           + v1.x*v1.x + v1.y*v1.y + v1.z*v1.z + v1.w*v1.w;
  #pragma unroll
  for (int d = 1; d < 64; d <<= 1) ss += __shfl_xor(ss, d, 64);
  float rinv = rsqrtf(fmaxf(ss, 1e-24f));
  float f[8] = {v0.x, v0.y, v0.z, v0.w, v1.x, v1.y, v1.z, v1.w};
  unsigned o[8];
  #pragma unroll
  for (int e = 0; e < 8; ++e) {
    float x = f[e] * rinv;
    unsigned u = __builtin_bit_cast(unsigned, x);
    o[e] = (u + 0x7FFFu + ((u >> 16) & 1u)) >> 16;   // RNE f32->bf16
  }
  uint4 pack;
  pack.x = o[0] | (o[1] << 16);
  pack.y = o[2] | (o[3] << 16);
  pack.z = o[4] | (o[5] << 16);
  pack.w = o[6] | (o[7] << 16);
  ((uint4*)(Eb + (size_t)k * CDIM))[lane] = pack;
}

// ---------------- fused heterogeneous kernel ----------------
// grid 4096 x 256 thr. Odd blocks: gt-count stream over 2 exact (b,k) ANN slices
// (pure-BW, ~40 VGPR -> packs into gemm blocks' latency shadow). Even blocks:
// R3-verified fused GEMM: X -> regs -> bf16 pack -> LDS(dbuf) -> MFMA -> argmax -> counts.
__global__ __launch_bounds__(256, 2) void fused_kernel(
    const float* __restrict__ X, const float* __restrict__ ANN,
    const unsigned short* __restrict__ Eb,
    float* __restrict__ gt_count,
    int* __restrict__ pred_count, int* __restrict__ inter) {
  __shared__ unsigned int lds[2][64 * ROWU];
  __shared__ float s_v[4][64];
  __shared__ int   s_k[4][64];
  int tid = threadIdx.x;
  int bid = blockIdx.x;
  int lane = tid & 63;

  if (bid & 1) {
    // ---- gt-count block: slices 2g, 2g+1; 32 independent float4 loads in flight ----
    int g = bid >> 1;
    const float* A0 = ANN + (size_t)(2 * g) * HWSZ + 4 * tid;
    float s0 = 0.f, s1 = 0.f;
    #pragma unroll
    for (int i = 0; i < 16; ++i) {
      float4 u = *(const float4*)(A0 + (size_t)i * 1024);
      float4 v = *(const float4*)(A0 + HWSZ + (size_t)i * 1024);
      s0 += (u.x + u.y) + (u.z + u.w);
      s1 += (v.x + v.y) + (v.z + v.w);
    }
    #pragma unroll
    for (int d = 1; d < 64; d <<= 1) {
      s0 += __shfl_xor(s0, d, 64);
      s1 += __shfl_xor(s1, d, 64);
    }
    if (lane == 0) { s_v[tid >> 6][0] = s0; s_v[tid >> 6][1] = s1; }
    __syncthreads();
    if (tid == 0) {   // exact integer partials -> order-independent float atomics
      atomicAdd(&gt_count[(2 * g) & (KDIM - 1)],
                s_v[0][0] + s_v[1][0] + s_v[2][0] + s_v[3][0]);
      atomicAdd(&gt_count[(2 * g + 1) & (KDIM - 1)],
                s_v[0][1] + s_v[1][1] + s_v[2][1] + s_v[3][1]);
    }
    return;
  }

  // ---- gemm block: 64 px x 512 cls; 4 waves, wave = 64px x 128cls, acc[4][8] ----
  int wv  = tid >> 6;           // k-group 0..3 (128 cls each)
  int p15 = lane & 15, q = lane >> 4;
  int cpair = tid >> 4;         // c-pair 0..15  (px-fastest map: 4-seg 256B staging runs)
  int px4   = tid & 15;         // px-quad 0..15
  int pxblk = bid >> 1;
  int px0 = pxblk * 64;
  int b   = px0 >> 14;
  int hw  = px0 & (HWSZ - 1);

  const float*          Xs = X  + ((size_t)b * CDIM + 2 * cpair) * HWSZ + hw + 4 * px4;
  const unsigned short* Er = Eb + (size_t)(wv * 128 + p15) * CDIM + q * 8;

  // stage slice 0 into lds[0]
  {
    float4 v0 = *(const float4*)Xs;
    float4 v1 = *(const float4*)(Xs + HWSZ);
    float f0[4] = {v0.x, v0.y, v0.z, v0.w};
    float f1[4] = {v1.x, v1.y, v1.z, v1.w};
    #pragma unroll
    for (int j = 0; j < 4; ++j)
      lds[0][(4 * px4 + j) * ROWU + cpair] = pack2bf16(f0[j], f1[j]);
  }

  f32x4 acc[4][8];
  #pragma unroll
  for (int m = 0; m < 4; ++m)
    #pragma unroll
    for (int n = 0; n < 8; ++n)
      acc[m][n] = (f32x4){0.f, 0.f, 0.f, 0.f};

  for (int cs = 0; cs < 16; ++cs) {
    int cur = cs & 1;
    // B frags for this slice (L2-resident) — issued before barrier
    bf16x8 bb[8];
    #pragma unroll
    for (int n = 0; n < 8; ++n)
      bb[n] = *(const bf16x8*)(Er + (size_t)n * 16 * CDIM + cs * 32);
    // prefetch next X slice into regs (issue before barrier; write after MFMA)
    float4 w0, w1;
    if (cs < 15) {
      const float* nsrc = Xs + (size_t)(cs + 1) * 32 * HWSZ;
      w0 = *(const float4*)nsrc;
      w1 = *(const float4*)(nsrc + HWSZ);
    }
    __syncthreads();                       // lds[cur] ready for all waves
    bf16x8 a[4];
    #pragma unroll
    for (int m = 0; m < 4; ++m)
      a[m] = *(bf16x8*)&lds[cur][(m * 16 + p15) * ROWU + q * 4];  // ds_read_b128
    __builtin_amdgcn_s_setprio(1);
    #pragma unroll
    for (int n = 0; n < 8; ++n)
      #pragma unroll
      for (int m = 0; m < 4; ++m)
        acc[m][n] = __builtin_amdgcn_mfma_f32_16x16x32_bf16(a[m], bb[n], acc[m][n], 0, 0, 0);
    __builtin_amdgcn_s_setprio(0);
    // write prefetched slice into the other buffer
    if (cs < 15) {
      float f0[4] = {w0.x, w0.y, w0.z, w0.w};
      float f1[4] = {w1.x, w1.y, w1.z, w1.w};
      #pragma unroll
      for (int j = 0; j < 4; ++j)
        lds[cur ^ 1][(4 * px4 + j) * ROWU + cpair] = pack2bf16(f0[j], f1[j]);
    }
  }

  // ---- argmax epilogue: D layout col(cls)=lane&15, row(px)=(lane>>4)*4+reg ----
  #pragma unroll
  for (int m = 0; m < 4; ++m) {
    #pragma unroll
    for (int r = 0; r < 4; ++r) {
      float best = acc[m][0][r];
      int bn = 0;
      #pragma unroll
      for (int n = 1; n < 8; ++n) {
        float v = acc[m][n][r];
        if (v > best) { best = v; bn = n; }
      }
      int bk = wv * 128 + bn * 16 + p15;
      #pragma unroll
      for (int d = 1; d < 16; d <<= 1) {   // butterfly over 16 cls-col lanes
        float ov = __shfl_xor(best, d, 64);
        int   ok = __shfl_xor(bk, d, 64);
        if (ov > best || (ov == best && ok < bk)) { best = ov; bk = ok; }
      }
      if (p15 == 0) {
        int p = m * 16 + q * 4 + r;        // pixel within block
        s_v[wv][p] = best;
        s_k[wv][p] = bk;
      }
    }
  }
  __syncthreads();
  if (tid < 64) {
    int p = tid;
    float best = s_v[0][p]; int bk = s_k[0][p];
    #pragma unroll
    for (int w = 1; w < 4; ++w) {
      float v = s_v[w][p]; int kk = s_k[w][p];
      if (v > best || (v == best && kk < bk)) { best = v; bk = kk; }
    }
    atomicAdd(&pred_count[bk], 1);
    float g = ANN[((size_t)b * KDIM + bk) * HWSZ + hw + p];   // one-hot gather
    if (g > 0.5f) atomicAdd(&inter[bk], 1);
  }
}

// ---------------- final dice reduction ----------------
__global__ __launch_bounds__(512) void final_kernel(
    const int* __restrict__ pred_count, const int* __restrict__ inter,
    const float* __restrict__ gt_count, float* __restrict__ out) {
  int k = threadIdx.x;
  float G = gt_count[k];
  float P = (float)pred_count[k];
  float I = (float)inter[k];
  float card  = P + G;
  float score = (2.f * I + 1e-4f) / fmaxf(card + 1e-4f, 1e-7f);
  float v = (G > 0.f) ? (1.f - score) : 0.f;
  #pragma unroll
  for (int d = 1; d < 64; d <<= 1) v += __shfl_xor(v, d, 64);
  __shared__ float sw[8];
  if ((k & 63) == 0) sw[k >> 6] = v;
  __syncthreads();
  if (k == 0) {
    float s = 0.f;
    #pragma unroll
    for (int i = 0; i < 8; ++i) s += sw[i];
    out[0] = s / (float)KDIM;
  }
}

extern "C" void kernel_launch(void* const* d_in, const int* in_sizes, int n_in,
                              void* d_out, int out_size, void* d_ws, size_t ws_size,
                              hipStream_t stream) {
  const float* X   = (const float*)d_in[0];   // [8,512,128,128] fp32
  const float* ANN = (const float*)d_in[1];   // [8,512,128,128] fp32 one-hot
  const float* E   = (const float*)d_in[2];   // [512,512] fp32

  char* base = (char*)d_ws;
  unsigned short* Eb = (unsigned short*)base;                 // 512 KiB @0
  float* gt_count    = (float*)(base + 524288);               // 2 KiB
  int*   pred_count  = (int*)  (base + 524288 + 2048);
  int*   inter       = (int*)  (base + 524288 + 4096);

  prep_emb_kernel<<<KDIM, 64, 0, stream>>>(E, Eb, gt_count);
  // even blocks: 2048 gemm tiles (64px x 512cls, R3-verified core);
  // odd blocks:  2048 gt-count streams (2 ANN slices each) — fill gemm latency stalls
  fused_kernel<<<4096, 256, 0, stream>>>(X, ANN, Eb, gt_count, pred_count, inter);
  final_kernel<<<1, 512, 0, stream>>>(pred_count, inter, gt_count, (float*)d_out);
}